// Round 16
// baseline (1201.373 us; speedup 1.0000x reference)
//
#include <hip/hip_runtime.h>
#include <math.h>

#define D 256          // feature dim (fixed by reference)
#define NREL 16        // relation count
#define CHUNK 6250     // nodes per dst-chunk (2 x f32 LDS arrays = 50 KB)
#define NCH 8          // max chunks (n <= NCH*CHUNK for bucketed path)
#define BPCB 16        // slices per chunk (bucketed scan): 128 blocks
#define BPC 32         // fallback scan slices per chunk

typedef float f4v __attribute__((ext_vector_type(4)));
typedef __attribute__((ext_vector_type(8))) short bf16x8;
typedef __attribute__((ext_vector_type(4))) float f32x4;

__device__ __forceinline__ short f2bf(float f) {
    union { float f; unsigned u; } v; v.f = f;
    unsigned r = v.u + 0x7FFFu + ((v.u >> 16) & 1u);
    return (short)(r >> 16);
}

// ---------------------------------------------------------------------------
// Kernel A (MFMA, proven R15): y[n][r] = dot(x[n], W[r]), xr[n] = x.root.
// Block 0 additionally zeroes the 8 bucket counters (runs before prep).
// ---------------------------------------------------------------------------
__global__ __launch_bounds__(256) void rgcn_y_kernel(
    const float* __restrict__ x, const float* __restrict__ w,
    const float* __restrict__ root, float* __restrict__ y,
    float* __restrict__ xr, unsigned* __restrict__ bcnt, int n)
{
    if (blockIdx.x == 0 && threadIdx.x < NCH) bcnt[threadIdx.x] = 0u;

    const int t    = threadIdx.x;
    const int l    = t & 63;
    const int wv   = t >> 6;
    const int base = blockIdx.x * 64 + wv * 16;
    const int arow = l & 15;      // A row = node-in-tile; also B/D col = rel
    const int kgrp = l >> 4;      // 0..3

    const bool okA = (base + arow) < n;
    const float* xp = x + (size_t)(base + arow) * D + kgrp * 8;
    const float* wp = w + (size_t)arow * D + kgrp * 8;
    const float* rp = root + kgrp * 8;

    f32x4 acc  = {0.f, 0.f, 0.f, 0.f};
    f32x4 accR = {0.f, 0.f, 0.f, 0.f};

    #pragma unroll
    for (int kk = 0; kk < 8; ++kk) {
        float4 xa = make_float4(0.f, 0.f, 0.f, 0.f), xb = xa;
        if (okA) {
            xa = *reinterpret_cast<const float4*>(xp + kk * 32);
            xb = *reinterpret_cast<const float4*>(xp + kk * 32 + 4);
        }
        bf16x8 af;
        af[0] = f2bf(xa.x); af[1] = f2bf(xa.y);
        af[2] = f2bf(xa.z); af[3] = f2bf(xa.w);
        af[4] = f2bf(xb.x); af[5] = f2bf(xb.y);
        af[6] = f2bf(xb.z); af[7] = f2bf(xb.w);

        float4 wa = *reinterpret_cast<const float4*>(wp + kk * 32);
        float4 wb = *reinterpret_cast<const float4*>(wp + kk * 32 + 4);
        bf16x8 bfr;
        bfr[0] = f2bf(wa.x); bfr[1] = f2bf(wa.y);
        bfr[2] = f2bf(wa.z); bfr[3] = f2bf(wa.w);
        bfr[4] = f2bf(wb.x); bfr[5] = f2bf(wb.y);
        bfr[6] = f2bf(wb.z); bfr[7] = f2bf(wb.w);

        acc = __builtin_amdgcn_mfma_f32_16x16x32_bf16(af, bfr, acc, 0, 0, 0);

        bf16x8 rf = {0, 0, 0, 0, 0, 0, 0, 0};
        if (arow == 0) {
            float4 ra = *reinterpret_cast<const float4*>(rp + kk * 32);
            float4 rb = *reinterpret_cast<const float4*>(rp + kk * 32 + 4);
            rf[0] = f2bf(ra.x); rf[1] = f2bf(ra.y);
            rf[2] = f2bf(ra.z); rf[3] = f2bf(ra.w);
            rf[4] = f2bf(rb.x); rf[5] = f2bf(rb.y);
            rf[6] = f2bf(rb.z); rf[7] = f2bf(rb.w);
        }
        accR = __builtin_amdgcn_mfma_f32_16x16x32_bf16(af, rf, accR, 0, 0, 0);
    }

    #pragma unroll
    for (int reg = 0; reg < 4; ++reg) {
        int node = base + kgrp * 4 + reg;
        if (node < n) {
            y[(size_t)node * NREL + arow] = acc[reg];
            if (arow == 0) xr[node] = accR[reg];
        }
    }
}

// ---------------------------------------------------------------------------
// Kernel P: bucket edges by dst-chunk. One pass; wave-aggregated tickets
// (one atomicAdd per chunk per wave); 8B records (src, loc | et<<16).
// ---------------------------------------------------------------------------
__global__ __launch_bounds__(256) void rgcn_bucket_kernel(
    const int* __restrict__ src, const int* __restrict__ dst,
    const int* __restrict__ et, unsigned* __restrict__ bcnt,
    uint2* __restrict__ buckets, int e, int cap)
{
    const int i = blockIdx.x * 256 + threadIdx.x;
    const int lane = threadIdx.x & 63;
    const bool valid = (i < e);

    int d_ = valid ? dst[i] : 0;
    int s_ = valid ? src[i] : 0;
    int r_ = valid ? et[i]  : 0;
    unsigned c = (unsigned)d_ / (unsigned)CHUNK;   // 0..7
    unsigned loc = (unsigned)d_ - c * CHUNK;

    #pragma unroll
    for (unsigned cc = 0; cc < NCH; ++cc) {
        unsigned long long m = __ballot(valid && (c == cc));
        if (m) {
            int leader = __ffsll((unsigned long long)m) - 1;
            unsigned base = 0;
            if (lane == leader)
                base = atomicAdd(&bcnt[cc], (unsigned)__popcll(m));
            base = __shfl(base, leader);
            if (valid && c == cc) {
                unsigned pos = base +
                    (unsigned)__popcll(m & ((lane == 0) ? 0ull
                                            : ((1ull << lane) - 1ull)));
                if (pos < (unsigned)cap)
                    buckets[(size_t)cc * cap + pos] =
                        make_uint2((unsigned)s_, loc | ((unsigned)r_ << 16));
            }
        }
    }
}

// ---------------------------------------------------------------------------
// Kernel B2: bucketed scan. Block (c,b): read slice b of bucket c (all hits,
// coalesced uint2), gather y, LDS accumulate, flush (sum,cnt) partials.
// ---------------------------------------------------------------------------
__global__ __launch_bounds__(1024) void rgcn_bscan_kernel(
    const unsigned* __restrict__ bcnt, const uint2* __restrict__ buckets,
    const float* __restrict__ y, float2* __restrict__ partial, int cap)
{
    __shared__ float lsum[CHUNK];
    __shared__ float lcnt[CHUNK];
    const int t = threadIdx.x;
    const int c = blockIdx.x >> 4;          // /BPCB
    const int b = blockIdx.x & (BPCB - 1);

    for (int j = t; j < CHUNK; j += 1024) { lsum[j] = 0.f; lcnt[j] = 0.f; }
    __syncthreads();

    int nc = (int)min(bcnt[c], (unsigned)cap);
    int sl = (nc + BPCB - 1) / BPCB;
    int s0 = b * sl;
    int s1 = min(s0 + sl, nc);
    const uint2* bp = buckets + (size_t)c * cap;

    for (int i = s0 + t; i < s1; i += 1024) {
        uint2 r = bp[i];
        float v = y[(size_t)r.x * NREL + (r.y >> 16)];
        atomicAdd(&lsum[r.y & 0xFFFFu], v);
        atomicAdd(&lcnt[r.y & 0xFFFFu], 1.0f);
    }
    __syncthreads();

    float2* p = partial + ((size_t)(c * BPCB + b)) * CHUNK;
    for (int j = t; j < CHUNK; j += 1024)
        p[j] = make_float2(lsum[j], lcnt[j]);
}

// ---------------------------------------------------------------------------
// Kernel C (fused finish), 32 nodes/block, BPCB=16 partials per node.
// ---------------------------------------------------------------------------
__global__ __launch_bounds__(256) void rgcn_finish_kernel(
    const float2* __restrict__ partial, const float* __restrict__ xr,
    const float* __restrict__ bias, const float* __restrict__ x,
    float* __restrict__ out_x, float* __restrict__ out_score, int n)
{
    __shared__ float ssum[32], scnt[32], sc[32];
    const int t = threadIdx.x;
    const int base = blockIdx.x * 32;

    if (t < 32) { ssum[t] = 0.f; scnt[t] = 0.f; }
    __syncthreads();

    {
        int nl = t & 31;
        int bg = t >> 5;                 // 0..7, covers BPCB=16 in 2s
        int node = base + nl;
        float s = 0.f, cN = 0.f;
        if (node < n) {
            int c = node / CHUNK;
            int j = node - c * CHUNK;
            const float2* p = partial + (size_t)c * BPCB * CHUNK + j;
            #pragma unroll
            for (int bb = 0; bb < 2; ++bb) {
                float2 v = p[(size_t)(bg * 2 + bb) * CHUNK];
                s += v.x; cN += v.y;
            }
        }
        atomicAdd(&ssum[nl], s);
        atomicAdd(&scnt[nl], cN);
    }
    __syncthreads();

    if (t < 32) {
        int node = base + t;
        if (node < n) {
            float m = ssum[t] / fmaxf(scnt[t], 1.0f);
            float v = tanhf(m + xr[node] + bias[0]);
            sc[t] = v;
            out_score[node] = v;
        }
    }
    __syncthreads();

    #pragma unroll
    for (int k = 0; k < 8; ++k) {
        int nl = k * 4 + (t >> 6);       // node local 0..31
        int f4 = t & 63;                 // float4 index in row
        int node = base + nl;
        if (node < n) {
            float s = sc[nl];
            float4 v = *reinterpret_cast<const float4*>(
                           x + (size_t)node * D + f4 * 4);
            v.x *= s; v.y *= s; v.z *= s; v.w *= s;
            f4v vo = {v.x, v.y, v.z, v.w};
            __builtin_nontemporal_store(
                vo, (f4v*)(out_x + (size_t)node * D + f4 * 4));
        }
    }
}

// ===================== fallback path (R8, scratch in out tail) ==============
__global__ __launch_bounds__(1024) void rgcn_edge_scan_kernel(
    const int* __restrict__ src, const int* __restrict__ dst,
    const int* __restrict__ et, const float* __restrict__ y,
    float2* __restrict__ partial, int e, int sl)
{
    __shared__ float lsum[CHUNK];
    __shared__ float lcnt[CHUNK];
    const int t = threadIdx.x;
    const int c = blockIdx.x / BPC;
    const int b = blockIdx.x % BPC;
    const int base = c * CHUNK;

    for (int j = t; j < CHUNK; j += 1024) { lsum[j] = 0.f; lcnt[j] = 0.f; }
    __syncthreads();

    const int slice0 = b * sl;
    const int rem = e - slice0;
    if (rem > 0) {
        const int gmax = (min(sl, rem) + 3) >> 2;
        for (int g = t; g < gmax; g += 1024) {
            int idx = slice0 + g * 4;
            if (idx + 3 < e) {
                int4 d4 = *reinterpret_cast<const int4*>(dst + idx);
                int4 s4 = *reinterpret_cast<const int4*>(src + idx);
                int4 r4 = *reinterpret_cast<const int4*>(et + idx);
                int loc0 = d4.x - base, loc1 = d4.y - base;
                int loc2 = d4.z - base, loc3 = d4.w - base;
                if ((unsigned)loc0 < (unsigned)CHUNK) {
                    atomicAdd(&lsum[loc0], y[(size_t)s4.x * NREL + r4.x]);
                    atomicAdd(&lcnt[loc0], 1.0f);
                }
                if ((unsigned)loc1 < (unsigned)CHUNK) {
                    atomicAdd(&lsum[loc1], y[(size_t)s4.y * NREL + r4.y]);
                    atomicAdd(&lcnt[loc1], 1.0f);
                }
                if ((unsigned)loc2 < (unsigned)CHUNK) {
                    atomicAdd(&lsum[loc2], y[(size_t)s4.z * NREL + r4.z]);
                    atomicAdd(&lcnt[loc2], 1.0f);
                }
                if ((unsigned)loc3 < (unsigned)CHUNK) {
                    atomicAdd(&lsum[loc3], y[(size_t)s4.w * NREL + r4.w]);
                    atomicAdd(&lcnt[loc3], 1.0f);
                }
            } else {
                for (int k = idx; k < e && k < idx + 4; ++k) {
                    int loc = dst[k] - base;
                    if ((unsigned)loc < (unsigned)CHUNK) {
                        atomicAdd(&lsum[loc], y[(size_t)src[k] * NREL + et[k]]);
                        atomicAdd(&lcnt[loc], 1.0f);
                    }
                }
            }
        }
    }
    __syncthreads();

    float2* p = partial + ((size_t)(c * BPC + b)) * CHUNK;
    for (int j = t; j < CHUNK; j += 1024)
        p[j] = make_float2(lsum[j], lcnt[j]);
}

__global__ __launch_bounds__(256) void rgcn_reduce_score_kernel(
    const float2* __restrict__ partial, const float* __restrict__ xr,
    const float* __restrict__ bias, float* __restrict__ score, int n)
{
    int i = blockIdx.x * 256 + threadIdx.x;
    if (i < n) {
        int c = i / CHUNK;
        int j = i - c * CHUNK;
        const float2* p = partial + (size_t)c * BPC * CHUNK + j;
        float s = 0.f, cN = 0.f;
        #pragma unroll 8
        for (int b = 0; b < BPC; ++b) {
            float2 v = p[(size_t)b * CHUNK];
            s += v.x; cN += v.y;
        }
        float m = s / fmaxf(cN, 1.0f);
        score[i] = tanhf(m + xr[i] + bias[0]);
    }
}

__global__ __launch_bounds__(256) void rgcn_scale_kernel(
    const float* __restrict__ x, const float* __restrict__ score,
    float* __restrict__ xo, int n)
{
    int gid = blockIdx.x * 256 + threadIdx.x;
    int node = gid >> 6;
    int f4 = gid & 63;
    if (node < n) {
        float s = score[node];
        float4 v = *reinterpret_cast<const float4*>(
                       x + (size_t)node * D + f4 * 4);
        v.x *= s; v.y *= s; v.z *= s; v.w *= s;
        *reinterpret_cast<float4*>(xo + (size_t)node * D + f4 * 4) = v;
    }
}

extern "C" void kernel_launch(void* const* d_in, const int* in_sizes, int n_in,
                              void* d_out, int out_size, void* d_ws, size_t ws_size,
                              hipStream_t stream)
{
    const float* x    = (const float*)d_in[0];
    const int*   ei   = (const int*)d_in[1];   // (2, E): src then dst
    const int*   et   = (const int*)d_in[2];
    const float* w    = (const float*)d_in[3]; // (R, D, 1) -> flat r*D+d
    const float* root = (const float*)d_in[4]; // (D, 1)    -> flat d
    const float* bias = (const float*)d_in[5];

    const int n = in_sizes[0] / D;   // 50000
    const int e = in_sizes[2];       // 800000

    float* out       = (float*)d_out;
    float* out_x     = out;                       // n*D floats
    float* out_score = out + (size_t)n * D;       // n floats

    const int cap = e / NCH + 8192;               // bucket capacity (>>8 sigma)

    // Bucketed-path scratch layout (floats):
    //   bcnt (16) | buckets (NCH*cap uint2 = NCH*cap*2) |
    //   partial (NCH*BPCB*CHUNK float2) | y (16n) | xr (n)
    const size_t buck_f = (size_t)NCH * cap * 2;
    const size_t partB_f = (size_t)NCH * BPCB * CHUNK * 2;
    const size_t needB_f = 16 + buck_f + partB_f + (size_t)n * (NREL + 1);
    const bool bucketed = (ws_size >= needB_f * sizeof(float)) &&
                          (n <= NCH * CHUNK);

    if (bucketed) {
        float* sb = (float*)d_ws;
        unsigned* bcnt  = (unsigned*)sb;
        uint2* buckets  = (uint2*)(sb + 16);
        float2* partial = (float2*)(sb + 16 + buck_f);
        float* y  = sb + 16 + buck_f + partB_f;
        float* xr = y + (size_t)n * NREL;

        rgcn_y_kernel<<<dim3((n + 63) / 64), dim3(256), 0, stream>>>(
            x, w, root, y, xr, bcnt, n);
        rgcn_bucket_kernel<<<dim3((e + 255) / 256), dim3(256), 0, stream>>>(
            ei, ei + e, et, bcnt, buckets, e, cap);
        rgcn_bscan_kernel<<<dim3(NCH * BPCB), dim3(1024), 0, stream>>>(
            bcnt, buckets, y, partial, cap);
        rgcn_finish_kernel<<<dim3((n + 31) / 32), dim3(256), 0, stream>>>(
            partial, xr, bias, x, out_x, out_score, n);
        return;
    }

    // -------- fallback: R8 path with scratch in the out tail --------
    const int C = (n + CHUNK - 1) / CHUNK;
    const int sl = ((((e + BPC - 1) / BPC) + 3) & ~3);
    const size_t part_f = (size_t)C * BPC * CHUNK * 2;
    const size_t need_f = part_f + (size_t)n * (NREL + 1) + 16;
    float* sb;
    const bool use_ws = (ws_size >= need_f * sizeof(float));
    if (use_ws)
        sb = (float*)d_ws;
    else {
        size_t ts = (((size_t)n * D - need_f) & ~(size_t)1);
        sb = out_x + ts;
    }
    float2* partial = (float2*)sb;
    float*  y  = sb + part_f;
    float*  xr = y + (size_t)n * NREL;
    unsigned* bcnt = (unsigned*)(xr + n);   // scratch (unused results)

    rgcn_y_kernel<<<dim3((n + 63) / 64), dim3(256), 0, stream>>>(
        x, w, root, y, xr, bcnt, n);
    rgcn_edge_scan_kernel<<<dim3(C * BPC), dim3(1024), 0, stream>>>(
        ei, ei + e, et, y, partial, e, sl);
    rgcn_reduce_score_kernel<<<dim3((n + 255) / 256), dim3(256), 0, stream>>>(
        partial, xr, bias, out_score, n);
    rgcn_scale_kernel<<<dim3((int)(((size_t)n * 64 + 255) / 256)), dim3(256), 0, stream>>>(
        x, out_score, out_x, n);
}